// Round 10
// baseline (413.323 us; speedup 1.0000x reference)
//
#include <hip/hip_runtime.h>
#include <hip/hip_bf16.h>
#include <math.h>

// Problem constants: b=2, s=2048, d_in=2048, nh=16, kv=4, hd=128
#define B  2
#define S  2048
#define D  2048
#define NH 16
#define KV 4
#define HD 128
#define G  (NH / KV)   // 4
#define M_ROWS (B * S) // 4096

typedef __hip_bfloat16 bf16;
typedef __attribute__((ext_vector_type(8))) short s16x8;   // 8 bf16 (4 VGPRs)
typedef __attribute__((ext_vector_type(4))) float f32x4;   // MFMA acc

__device__ __forceinline__ short bf16_bits(float f) {
    bf16 t = __float2bfloat16(f);
    return *reinterpret_cast<short*>(&t);
}

// async global->LDS, 16B per lane; LDS dest = wave-uniform base + lane*16
__device__ __forceinline__ void gload16(const void* g, void* l) {
    __builtin_amdgcn_global_load_lds(
        (const __attribute__((address_space(1))) void*)g,
        (__attribute__((address_space(3))) void*)l, 16, 0, 0);
}

// ---------------------------------------------------------------------------
// fp32 -> bf16 cast (4 elems/thread)
// ---------------------------------------------------------------------------
__global__ __launch_bounds__(256) void cast_f32_bf16(const float* __restrict__ in,
                                                     bf16* __restrict__ o, int n4) {
    int i = blockIdx.x * 256 + threadIdx.x;
    if (i >= n4) return;
    float4 v = ((const float4*)in)[i];
    ushort4 u;
    u.x = (unsigned short)bf16_bits(v.x);
    u.y = (unsigned short)bf16_bits(v.y);
    u.z = (unsigned short)bf16_bits(v.z);
    u.w = (unsigned short)bf16_bits(v.w);
    ((ushort4*)o)[i] = u;
}

// ---------------------------------------------------------------------------
// W (K x N fp32, row-major) -> Wt (N x K bf16, row-major), tiled transpose
// ---------------------------------------------------------------------------
__global__ __launch_bounds__(256) void tcast(const float* __restrict__ W,
                                             bf16* __restrict__ Wt, int K, int N) {
    __shared__ float T[32][33];
    const int n0 = blockIdx.x * 32, k0 = blockIdx.y * 32;
    const int tx = threadIdx.x & 31, ty = threadIdx.x >> 5; // ty 0..7
#pragma unroll
    for (int i = 0; i < 4; i++)
        T[ty + i * 8][tx] = W[(size_t)(k0 + ty + i * 8) * N + n0 + tx];
    __syncthreads();
#pragma unroll
    for (int i = 0; i < 4; i++)
        Wt[(size_t)(n0 + ty + i * 8) * K + k0 + tx] = __float2bfloat16(T[tx][ty + i * 8]);
}

// ---------------------------------------------------------------------------
// MFMA GEMM: A (M x K bf16) @ Bt (N x K bf16) -> out.
// Block tile 128x128, BK=64 single-buffer (half the barrier drains of BK=32;
// LDS 32 KB keeps >=5 blocks/CU capacity, avoiding m132's BK=128 trap).
// 4 waves (64x64 quadrant, 4x4 of 16x16x32 MFMA, 2 K-slices per tile).
// Staging via global_load_lds width=16 (linear LDS, stride 64 shorts).
// XCD-aware swizzle (T1): nwg%8==0 for both call sites.
// MODE 0: fp32 out0[m*N+n]
// MODE 3: fused QKV epilogue, N=3072:
//    n <  2048        -> q fp32 head-major out0[((b*16+h)*S+si)*HD+d]
//    2048 <= n < 2560 -> k fp32 head-major out1[((b*4+h)*S+si)*HD+d]
//    n >= 2560        -> v bf16 V^T       out2[((b*4+h)*HD+d)*S+si]
// ---------------------------------------------------------------------------
template<int MODE>
__global__ __launch_bounds__(256) void gemm_bt(const bf16* __restrict__ A,
                                               const bf16* __restrict__ Bt,
                                               void* __restrict__ out0,
                                               void* __restrict__ out1,
                                               void* __restrict__ out2,
                                               int N, int K) {
    // XCD swizzle: orig%8 = XCD; give each XCD a contiguous chunk of work.
    const int gx  = gridDim.x;
    const int nwg = gx * gridDim.y;
    const int cpx = nwg >> 3;                    // nwg % 8 == 0 at both call sites
    int wg = blockIdx.y * gx + blockIdx.x;
    wg = (wg & 7) * cpx + (wg >> 3);
    const int m0 = (wg / gx) * 128;
    const int n0 = (wg % gx) * 128;

    const int tid  = threadIdx.x;
    const int wave = tid >> 6;
    const int lane = tid & 63;
    const int mw = (wave >> 1) * 64;
    const int nw = (wave & 1) * 64;

    __shared__ short Al[128 * 64];   // linear, 128B rows (gload_lds dest), 16 KB
    __shared__ short Bl[128 * 64];

    f32x4 acc[4][4] = {};

    const int fr = lane & 15;
    const int fq = (lane >> 4) * 8;

    // staging geometry: wave w stages rows [w*32, w*32+32) of A and B;
    // each gload16 call covers 8 rows (64 lanes x 16B = 1KB = 8 x 128B rows):
    //   lane -> row r0 + c*8 + (lane>>3), col-slot (lane&7)*8 shorts
    const int r0  = wave * 32;
    const int srl = lane >> 3;
    const int scl = (lane & 7) * 8;

    for (int k0 = 0; k0 < K; k0 += 64) {
        __syncthreads();    // previous compute done reading LDS
#pragma unroll
        for (int c = 0; c < 4; c++) {
            gload16(A  + (size_t)(m0 + r0 + c * 8 + srl) * K + k0 + scl, &Al[(r0 + c * 8) * 64]);
            gload16(Bt + (size_t)(n0 + r0 + c * 8 + srl) * K + k0 + scl, &Bl[(r0 + c * 8) * 64]);
        }
        __syncthreads();    // vmcnt(0) drain + barrier: tiles ready

#pragma unroll
        for (int ks = 0; ks < 2; ks++) {
            s16x8 af[4], bfr[4];
#pragma unroll
            for (int i = 0; i < 4; i++) {
                af[i]  = *(const s16x8*)(&Al[(mw + i * 16 + fr) * 64 + ks * 32 + fq]);
                bfr[i] = *(const s16x8*)(&Bl[(nw + i * 16 + fr) * 64 + ks * 32 + fq]);
            }
#pragma unroll
            for (int i = 0; i < 4; i++)
#pragma unroll
                for (int j = 0; j < 4; j++)
                    acc[i][j] = __builtin_amdgcn_mfma_f32_16x16x32_bf16(af[i], bfr[j], acc[i][j], 0, 0, 0);
        }
    }

    const int col_l = lane & 15;
    const int row_l = (lane >> 4) * 4;
#pragma unroll
    for (int i = 0; i < 4; i++)
#pragma unroll
        for (int j = 0; j < 4; j++) {
            int m_base = m0 + mw + i * 16 + row_l;   // 4 consecutive m
            int n = n0 + nw + j * 16 + col_l;
            if (MODE == 3 && n >= 2560) {
                // v: bf16 V^T, 4 consecutive si
                int nn = n - 2560;
                int bb = m_base >> 11, si = m_base & (S - 1);
                int hh = nn >> 7, d = nn & (HD - 1);
                ushort4 u;
                u.x = (unsigned short)bf16_bits(acc[i][j][0]);
                u.y = (unsigned short)bf16_bits(acc[i][j][1]);
                u.z = (unsigned short)bf16_bits(acc[i][j][2]);
                u.w = (unsigned short)bf16_bits(acc[i][j][3]);
                *(ushort4*)((bf16*)out2 + (((size_t)(bb * KV + hh)) * HD + d) * S + si) = u;
            } else {
#pragma unroll
                for (int r = 0; r < 4; r++) {
                    int m = m_base + r;
                    if (MODE == 3) {
                        int bb = m >> 11, si = m & (S - 1);
                        if (n < 2048) {
                            int h = n >> 7, d = n & (HD - 1);
                            ((float*)out0)[(((size_t)(bb * NH + h)) * S + si) * HD + d] = acc[i][j][r];
                        } else {
                            int nn = n - 2048;
                            int h = nn >> 7, d = nn & (HD - 1);
                            ((float*)out1)[(((size_t)(bb * KV + h)) * S + si) * HD + d] = acc[i][j][r];
                        }
                    } else {
                        ((float*)out0)[(size_t)m * N + n] = acc[i][j][r];
                    }
                }
            }
        }
}

// ---------------------------------------------------------------------------
// RMSNorm (over hd=128) + RoPE; fp32 head-major in -> bf16 same layout out.
// One wave per row, zero LDS, zero barriers. Lane holds (x[d], x[d+64]);
// cos/sin tables have duplicated halves so c[d]==c[d+64].
// SC: fold 1/sqrt(hd) into output (for Q).
// ---------------------------------------------------------------------------
template<bool SC>
__global__ __launch_bounds__(256) void rms_rope2(const float* __restrict__ in,
                                                 bf16* __restrict__ out,
                                                 const float* __restrict__ scale,
                                                 const float* __restrict__ cosT,
                                                 const float* __restrict__ sinT) {
    const int row  = blockIdx.x * 4 + (threadIdx.x >> 6);
    const int lane = threadIdx.x & 63;
    const int si   = row & (S - 1);
    const float* rp = in + (size_t)row * HD;

    float x1 = rp[lane];
    float x2 = rp[lane + 64];

    float ss = x1 * x1 + x2 * x2;
#pragma unroll
    for (int m = 1; m < 64; m <<= 1) ss += __shfl_xor(ss, m, 64);
    const float rinv = rsqrtf(ss * (1.0f / HD) + 1e-6f);

    const float n1 = x1 * rinv * scale[lane];
    const float n2 = x2 * rinv * scale[lane + 64];

    const float c = cosT[(size_t)si * HD + lane];
    const float s = sinT[(size_t)si * HD + lane];

    float r1 = n1 * c - n2 * s;   // d < 64: rot = -x[d+64]
    float r2 = n2 * c + n1 * s;   // d >= 64: rot = +x[d-64]
    if (SC) { r1 *= 0.08838834764831845f; r2 *= 0.08838834764831845f; }

    out[(size_t)row * HD + lane]      = __float2bfloat16(r1);
    out[(size_t)row * HD + lane + 64] = __float2bfloat16(r2);
}

// ---------------------------------------------------------------------------
// MFMA flash attention v4 (round-3/8 exact: measured 110 us; grid reverted
// from the round-9 XCD-local experiment, which cut FETCH 122->17 MB but cost
// +8 us from L2 contention -- flash is latency-bound, not fetch-bound).
// Head-merged, causally-paired, fixed-max softmax, TWO independent 4-wave
// groups per block (512 threads) splitting the 33-tile list [0,17)/[17,33).
// Fixed-max softmax => partial (o,l) over disjoint KV ranges are exactly
// additive; group 1 publishes its phase-B partials via LDS, group 0 merges.
// NO setprio (regressed: lockstep waves). K AND V staged into LDS
// (V-direct-from-L2 regressed: uncoalesced 16B x stride-2S reads).
// qb: (b,NH,S,HD) bf16 pre-scaled by 1/sqrt(hd); kb: (b,KV,S,HD) bf16;
// vtb: (b,KV,HD,S) bf16. ctx: (b,s,nh,hd) bf16.
// Scores bounded: ||q||=||k||=sqrt(128) => |s| <= 11.32; use fixed max 13.
// ---------------------------------------------------------------------------
__global__ __launch_bounds__(512) void flash_mfma4(const bf16* __restrict__ qb,
                                                   const bf16* __restrict__ kb,
                                                   const bf16* __restrict__ vtb,
                                                   bf16* __restrict__ ctx) {
    const int p    = blockIdx.x;         // pair index 0..31
    const int kvh  = blockIdx.y;
    const int b    = blockIdx.z;
    const int tid  = threadIdx.x;
    const int wave = tid >> 6;           // 0..7
    const int grp  = wave >> 2;          // 0: list [0,17), 1: list [17,33)
    const int wl   = wave & 3;           // head within KV group
    const int lane = tid & 63;
    const int tg   = tid & 255;          // tid within group (for staging)
    const int quad = lane >> 4;
    const int l16  = lane & 15;
    const int quad8 = quad * 8;
    const int h = kvh * G + wl;          // this wave's q-head

    __shared__ __align__(16) char pool[108544];
    short* KsG = (short*)(pool + grp * 17408);           // [64][136]
    short* VsG = (short*)(pool + 34816 + grp * 18432);   // [128][72]
    short* PsW = (short*)(pool + 71680 + wave * 4608);   // [32][72]
    float* oS  = (float*)pool;
    float* lS  = (float*)(pool + 65536);

    const bf16* qbase = qb  + ((size_t)(b * NH + h))   * S * HD;
    const bf16* kbase = kb  + ((size_t)(b * KV + kvh)) * S * HD;
    const bf16* vbase = vtb + ((size_t)(b * KV + kvh)) * HD * S;

    const int nA   = (p >> 1) + 1;       // KV tiles for q-tile p (1..16)
    const int pB   = 63 - p;
    const int iBeg = grp ? 17 : 0;
    const int iEnd = grp ? 33 : 17;      // nA + nB == 33 always

    int q0 = grp ? 32 * pB : 32 * p;

    // Q A-fragments: rows q0 + s*16 + l16, k = ks*32 + quad8
    s16x8 qf[2][4];
#pragma unroll
    for (int s = 0; s < 2; s++) {
        const bf16* qrow = qbase + (size_t)(q0 + s * 16 + l16) * HD + quad8;
#pragma unroll
        for (int ks = 0; ks < 4; ks++)
            qf[s][ks] = *(const s16x8*)(qrow + ks * 32);
    }

    f32x4 o[2][8] = {};
    float l[2][4] = {};

    // prologue: prefetch this group's first tile into regs
    uint4 kreg[4], vreg[4];
    {
        const int tf = (iBeg < nA) ? 64 * iBeg : 64 * (iBeg - nA);
#pragma unroll
        for (int it = 0; it < 4; it++) {
            int c = tg + it * 256;
            kreg[it] = *(const uint4*)(kbase + (size_t)(tf + (c >> 4)) * HD + (c & 15) * 8);
            vreg[it] = *(const uint4*)(vbase + (size_t)(c >> 3) * S + tf + (c & 7) * 8);
        }
    }

    for (int ii = 0; ii < 17; ii++) {
        const int i   = iBeg + ii;
        const bool act = (i < iEnd);     // grp1 idles on ii==16 (barrier parity)

        // commit prefetched tile to this group's LDS
        if (act) {
#pragma unroll
            for (int it = 0; it < 4; it++) {
                int c = tg + it * 256;
                *(uint4*)&KsG[(c >> 4) * 136 + (c & 15) * 8] = kreg[it];
                *(uint4*)&VsG[(c >> 3) * 72  + (c & 7)  * 8] = vreg[it];
            }
        }
        __syncthreads();   // both groups' tiles ready

        const int t0 = (i < nA) ? 64 * i : 64 * (i - nA);

        // issue next tile's global loads (in flight during compute)
        if (act && i + 1 < iEnd) {
            const int tn = (i + 1 < nA) ? 64 * (i + 1) : 64 * (i + 1 - nA);
#pragma unroll
            for (int it = 0; it < 4; it++) {
                int c = tg + it * 256;
                kreg[it] = *(const uint4*)(kbase + (size_t)(tn + (c >> 4)) * HD + (c & 15) * 8);
                vreg[it] = *(const uint4*)(vbase + (size_t)(c >> 3) * S + tn + (c & 7) * 8);
            }
        }

        if (act) {
            // ---- S = Q K^T : 32q x 64t per wave ----
            f32x4 sa[2][4] = {};
#pragma unroll
            for (int ks = 0; ks < 4; ks++) {
#pragma unroll
                for (int n = 0; n < 4; n++) {
                    s16x8 kf = *(const s16x8*)&KsG[(n * 16 + l16) * 136 + ks * 32 + quad8];
#pragma unroll
                    for (int s = 0; s < 2; s++)
                        sa[s][n] = __builtin_amdgcn_mfma_f32_16x16x32_bf16(qf[s][ks], kf, sa[s][n], 0, 0, 0);
                }
            }

            // ---- fixed-max exp: p = exp(s - 13); no reductions, no rescale ----
            const bool msk = (t0 + 63 > q0);  // only possibly true on a phase's last tile
#pragma unroll
            for (int s = 0; s < 2; s++)
#pragma unroll
                for (int r = 0; r < 4; r++) {
                    const int qg = q0 + s * 16 + quad * 4 + r;
#pragma unroll
                    for (int n = 0; n < 4; n++) {
                        float v = sa[s][n][r];
                        if (msk && (t0 + n * 16 + l16 > qg)) v = -INFINITY;
                        float pv = __expf(v - 13.0f);
                        l[s][r] += pv;
                        PsW[(s * 16 + quad * 4 + r) * 72 + n * 16 + l16] = bf16_bits(pv);
                    }
                }
            // Ps is per-wave: same-wave LDS write->read needs no barrier (proven R6).

            // ---- PV: O(32q x 128d) += P(32x64) V(64x128) ----
#pragma unroll
            for (int ks = 0; ks < 2; ks++) {
                s16x8 vf[8];
#pragma unroll
                for (int n = 0; n < 8; n++)
                    vf[n] = *(const s16x8*)&VsG[(n * 16 + l16) * 72 + ks * 32 + quad8];
#pragma unroll
                for (int s = 0; s < 2; s++) {
                    s16x8 pf = *(const s16x8*)&PsW[(s * 16 + l16) * 72 + ks * 32 + quad8];
#pragma unroll
                    for (int n = 0; n < 8; n++)
                        o[s][n] = __builtin_amdgcn_mfma_f32_16x16x32_bf16(pf, vf[n], o[s][n], 0, 0, 0);
                }
            }

            // ---- phase boundary (group 0 only; group 1's i >= 17 > nA-1):
            //      flush complete phase A, switch to q-tile 63-p ----
            if (i == nA - 1) {
#pragma unroll
                for (int s = 0; s < 2; s++)
#pragma unroll
                    for (int r = 0; r < 4; r++) {
                        float ls = l[s][r];
#pragma unroll
                        for (int m = 1; m < 16; m <<= 1) ls += __shfl_xor(ls, m, 64);
                        const float inv = 1.0f / ls;
                        const int qg = q0 + s * 16 + quad * 4 + r;
                        bf16* dst = ctx + (((size_t)(b * S + qg)) * NH + h) * HD;
#pragma unroll
                        for (int n = 0; n < 8; n++)
                            dst[n * 16 + l16] = __float2bfloat16(o[s][n][r] * inv);
                    }
                q0 = 32 * pB;
#pragma unroll
                for (int s = 0; s < 2; s++) {
                    const bf16* qrow = qbase + (size_t)(q0 + s * 16 + l16) * HD + quad8;
#pragma unroll
                    for (int ks = 0; ks < 4; ks++)
                        qf[s][ks] = *(const s16x8*)(qrow + ks * 32);
                }
#pragma unroll
                for (int s = 0; s < 2; s++) {
#pragma unroll
                    for (int n = 0; n < 8; n++) o[s][n] = (f32x4){0.f, 0.f, 0.f, 0.f};
#pragma unroll
                    for (int r = 0; r < 4; r++) l[s][r] = 0.0f;
                }
            }
        }

        __syncthreads();   // all waves done reading Ks/Vs before next commit
    }

    // ---- merge phase-B partials: grp1 -> LDS, grp0 adds + writes ----
    // (fixed-max softmax: disjoint-KV partials are additive in o and l)
    if (grp == 1) {
        float* oW = oS + wl * 64 * 64;
        float* lW = lS + wl * 8 * 64;
#pragma unroll
        for (int s = 0; s < 2; s++)
#pragma unroll
            for (int n = 0; n < 8; n++)
#pragma unroll
                for (int r = 0; r < 4; r++)
                    oW[((s * 8 + n) * 4 + r) * 64 + lane] = o[s][n][r];
#pragma unroll
        for (int s = 0; s < 2; s++)
#pragma unroll
            for (int r = 0; r < 4; r++)
                lW[(s * 4 + r) * 64 + lane] = l[s][r];
    }
    __syncthreads();
    if (grp == 0) {
        float* oW = oS + wl * 64 * 64;
        float* lW = lS + wl * 8 * 64;
#pragma unroll
        for (int s = 0; s < 2; s++)
#pragma unroll
            for (int r = 0; r < 4; r++) {
                float ls = l[s][r] + lW[(s * 4 + r) * 64 + lane];
#pragma unroll
                for (int m = 1; m < 16; m <<= 1) ls += __shfl_xor(ls, m, 64);
                const float inv = 1.0f / ls;
                const int qg = q0 + s * 16 + quad * 4 + r;   // q0 == 32*pB here
                bf16* dst = ctx + (((size_t)(b * S + qg)) * NH + h) * HD;
#pragma unroll
                for (int n = 0; n < 8; n++)
                    dst[n * 16 + l16] =
                        __float2bfloat16((o[s][n][r] + oW[((s * 8 + n) * 4 + r) * 64 + lane]) * inv);
            }
    }
}

// ---------------------------------------------------------------------------
extern "C" void kernel_launch(void* const* d_in, const int* in_sizes, int n_in,
                              void* d_out, int out_size, void* d_ws, size_t ws_size,
                              hipStream_t stream) {
    const float* x    = (const float*)d_in[0];
    const float* cosT = (const float*)d_in[2];
    const float* sinT = (const float*)d_in[3];
    const float* Wq   = (const float*)d_in[4];
    const float* Wk   = (const float*)d_in[5];
    const float* Wv   = (const float*)d_in[6];
    const float* Wo   = (const float*)d_in[7];
    const float* qsc  = (const float*)d_in[8];
    const float* ksc  = (const float*)d_in[9];
    float* out = (float*)d_out;

    // Workspace packing (72 MB total), byte offsets:
    // q_ws [0,32M) fp32 q head-major; wo_t [0,8M) after q dead;
    // ctx_b [8M,24M) after q dead; k_ws [32M,40M) fp32 k head-major;
    // xb [40M,56M); qb same region after projections;
    // wq_t [56M,64M), wk_t [64M,66M), wv_t [66M,68M) = contiguous Wqkv^T (N=3072);
    // kb [56M,64M) same region after projections; vtb [68M,72M).
    char* w = (char*)d_ws;
    float* q_ws = (float*)(w);
    bf16*  wo_t = (bf16*)(w);
    bf16*  ctx_b= (bf16*)(w + (8u << 20));
    float* k_ws = (float*)(w + (32u << 20));
    bf16*  xb   = (bf16*)(w + (40u << 20));
    bf16*  qb   = (bf16*)(w + (40u << 20));
    bf16*  wq_t = (bf16*)(w + (56u << 20));
    bf16*  kb   = (bf16*)(w + (56u << 20));
    bf16*  wk_t = (bf16*)(w + (64u << 20));
    bf16*  wv_t = (bf16*)(w + (66u << 20));
    bf16*  vtb  = (bf16*)(w + (68u << 20));

    // 1) casts / transposes
    cast_f32_bf16<<<(M_ROWS * D / 4 + 255) / 256, 256, 0, stream>>>(x, xb, M_ROWS * D / 4);
    tcast<<<dim3((NH * HD) / 32, D / 32), 256, 0, stream>>>(Wq, wq_t, D, NH * HD);
    tcast<<<dim3((KV * HD) / 32, D / 32), 256, 0, stream>>>(Wk, wk_t, D, KV * HD);
    tcast<<<dim3((KV * HD) / 32, D / 32), 256, 0, stream>>>(Wv, wv_t, D, KV * HD);

    // 2) fused QKV projection (MFMA, N=3072): q,k -> fp32 head-major; v -> bf16 V^T
    gemm_bt<3><<<dim3((NH * HD + 2 * KV * HD) / 128, M_ROWS / 128), 256, 0, stream>>>(
        xb, wq_t, q_ws, k_ws, vtb, NH * HD + 2 * KV * HD, D);

    // 3) RMSNorm + RoPE -> bf16 (q pre-scaled by 1/sqrt(hd)); 1 wave/row
    rms_rope2<true ><<<B * NH * S / 4, 256, 0, stream>>>(q_ws, qb, qsc, cosT, sinT);
    rms_rope2<false><<<B * KV * S / 4, 256, 0, stream>>>(k_ws, kb, ksc, cosT, sinT);

    // 4) Wo^T into dead q region
    tcast<<<dim3(D / 32, D / 32), 256, 0, stream>>>(Wo, wo_t, D, D);

    // 5) MFMA flash attention v4 (round-3 grid, best measured) -> bf16 ctx
    flash_mfma4<<<dim3(32, KV, B), 512, 0, stream>>>(qb, kb, vtb, ctx_b);

    // 6) output projection
    gemm_bt<0><<<dim3(D / 128, M_ROWS / 128), 256, 0, stream>>>(ctx_b, wo_t, out, nullptr, nullptr, D, D);
}

// Round 11
// 386.080 us; speedup vs baseline: 1.0706x; 1.0706x over previous
//
#include <hip/hip_runtime.h>
#include <hip/hip_bf16.h>
#include <math.h>

// Problem constants: b=2, s=2048, d_in=2048, nh=16, kv=4, hd=128
#define B  2
#define S  2048
#define D  2048
#define NH 16
#define KV 4
#define HD 128
#define G  (NH / KV)   // 4
#define M_ROWS (B * S) // 4096

typedef __hip_bfloat16 bf16;
typedef __attribute__((ext_vector_type(8))) short s16x8;   // 8 bf16 (4 VGPRs)
typedef __attribute__((ext_vector_type(4))) float f32x4;   // MFMA acc

__device__ __forceinline__ short bf16_bits(float f) {
    bf16 t = __float2bfloat16(f);
    return *reinterpret_cast<short*>(&t);
}

// async global->LDS, 16B per lane; LDS dest = wave-uniform base + lane*16
__device__ __forceinline__ void gload16(const void* g, void* l) {
    __builtin_amdgcn_global_load_lds(
        (const __attribute__((address_space(1))) void*)g,
        (__attribute__((address_space(3))) void*)l, 16, 0, 0);
}

// ---------------------------------------------------------------------------
// Fused prep: x fp32->bf16 cast + Wq/Wk/Wv transpose-casts, one launch.
// Block ranges: [0,8192) cast; [8192,12288) Wq; [12288,13312) Wk;
// [13312,14336) Wv. All pieces independent.
// ---------------------------------------------------------------------------
__device__ __forceinline__ void tcast_tile(const float* __restrict__ W,
                                           bf16* __restrict__ Wt,
                                           int K, int N, int n0, int k0, int tid,
                                           float (*T)[33]) {
    const int tx = tid & 31, ty = tid >> 5; // ty 0..7
#pragma unroll
    for (int i = 0; i < 4; i++)
        T[ty + i * 8][tx] = W[(size_t)(k0 + ty + i * 8) * N + n0 + tx];
    __syncthreads();
#pragma unroll
    for (int i = 0; i < 4; i++)
        Wt[(size_t)(n0 + ty + i * 8) * K + k0 + tx] = __float2bfloat16(T[tx][ty + i * 8]);
}

__global__ __launch_bounds__(256) void prep(const float* __restrict__ x,
                                            bf16* __restrict__ xb,
                                            const float* __restrict__ Wq,
                                            bf16* __restrict__ wq_t,
                                            const float* __restrict__ Wk,
                                            bf16* __restrict__ wk_t,
                                            const float* __restrict__ Wv,
                                            bf16* __restrict__ wv_t) {
    __shared__ float T[32][33];
    const int bid = blockIdx.x;
    const int tid = threadIdx.x;
    if (bid < 8192) {
        // fp32 -> bf16 cast, 4 elems/thread (float4)
        int i = bid * 256 + tid;                 // < M_ROWS*D/4 = 2097152
        float4 v = ((const float4*)x)[i];
        ushort4 u;
        u.x = (unsigned short)bf16_bits(v.x);
        u.y = (unsigned short)bf16_bits(v.y);
        u.z = (unsigned short)bf16_bits(v.z);
        u.w = (unsigned short)bf16_bits(v.w);
        ((ushort4*)xb)[i] = u;
    } else if (bid < 8192 + 4096) {
        int sub = bid - 8192;                    // Wq: N=2048 (64 n-tiles), K=2048
        tcast_tile(Wq, wq_t, D, NH * HD, (sub & 63) * 32, (sub >> 6) * 32, tid, T);
    } else if (bid < 8192 + 4096 + 1024) {
        int sub = bid - (8192 + 4096);           // Wk: N=512 (16 n-tiles)
        tcast_tile(Wk, wk_t, D, KV * HD, (sub & 15) * 32, (sub >> 4) * 32, tid, T);
    } else {
        int sub = bid - (8192 + 4096 + 1024);    // Wv: N=512
        tcast_tile(Wv, wv_t, D, KV * HD, (sub & 15) * 32, (sub >> 4) * 32, tid, T);
    }
}

// ---------------------------------------------------------------------------
// W (K x N fp32, row-major) -> Wt (N x K bf16, row-major), tiled transpose
// (standalone launch kept for Wo^T, whose dest overlays q_ws until rms done)
// ---------------------------------------------------------------------------
__global__ __launch_bounds__(256) void tcast(const float* __restrict__ W,
                                             bf16* __restrict__ Wt, int K, int N) {
    __shared__ float T[32][33];
    tcast_tile(W, Wt, K, N, blockIdx.x * 32, blockIdx.y * 32, threadIdx.x, T);
}

// ---------------------------------------------------------------------------
// MFMA GEMM: A (M x K bf16) @ Bt (N x K bf16) -> out.  (round-8 proven body)
// Block tile 128x128, BK=32, 4 waves (64x64 quadrant, 4x4 of 16x16x32 MFMA).
// Staging via global_load_lds width=16 (m97 structure, linear LDS, stride 32).
// XCD-aware swizzle (T1): nwg%8==0 for both call sites.
// MODE 0: fp32 out0[m*N+n]
// MODE 3: fused QKV epilogue, N=3072:
//    n <  2048        -> q fp32 head-major out0[((b*16+h)*S+si)*HD+d]
//    2048 <= n < 2560 -> k fp32 head-major out1[((b*4+h)*S+si)*HD+d]
//    n >= 2560        -> v bf16 V^T       out2[((b*4+h)*HD+d)*S+si]
// ---------------------------------------------------------------------------
template<int MODE>
__global__ __launch_bounds__(256) void gemm_bt(const bf16* __restrict__ A,
                                               const bf16* __restrict__ Bt,
                                               void* __restrict__ out0,
                                               void* __restrict__ out1,
                                               void* __restrict__ out2,
                                               int N, int K) {
    // XCD swizzle: orig%8 = XCD; give each XCD a contiguous chunk of work.
    const int gx  = gridDim.x;
    const int nwg = gx * gridDim.y;
    const int cpx = nwg >> 3;                    // nwg % 8 == 0 at both call sites
    int wg = blockIdx.y * gx + blockIdx.x;
    wg = (wg & 7) * cpx + (wg >> 3);
    const int m0 = (wg / gx) * 128;
    const int n0 = (wg % gx) * 128;

    const int tid  = threadIdx.x;
    const int wave = tid >> 6;
    const int lane = tid & 63;
    const int mw = (wave >> 1) * 64;
    const int nw = (wave & 1) * 64;

    __shared__ short Al[128 * 32];   // linear, 64B rows (gload_lds dest)
    __shared__ short Bl[128 * 32];

    f32x4 acc[4][4] = {};

    const int fr = lane & 15;
    const int fq = (lane >> 4) * 8;

    // staging geometry: wave w stages rows [w*32, w*32+32) of A and B;
    // each gload16 call covers 16 rows (64 lanes x 16B = 1KB):
    //   lane -> row r0 + (lane>>2), col-slot (lane&3)*8 shorts
    const int r0  = wave * 32;
    const int srl = lane >> 2;
    const int scl = (lane & 3) * 8;

    for (int k0 = 0; k0 < K; k0 += 32) {
        __syncthreads();    // previous compute done reading LDS
        gload16(A  + (size_t)(m0 + r0 +      srl) * K + k0 + scl, &Al[(r0     ) * 32]);
        gload16(A  + (size_t)(m0 + r0 + 16 + srl) * K + k0 + scl, &Al[(r0 + 16) * 32]);
        gload16(Bt + (size_t)(n0 + r0 +      srl) * K + k0 + scl, &Bl[(r0     ) * 32]);
        gload16(Bt + (size_t)(n0 + r0 + 16 + srl) * K + k0 + scl, &Bl[(r0 + 16) * 32]);
        __syncthreads();    // vmcnt(0) drain + barrier: tiles ready

        s16x8 af[4], bfr[4];
#pragma unroll
        for (int i = 0; i < 4; i++) {
            af[i]  = *(const s16x8*)(&Al[(mw + i * 16 + fr) * 32 + fq]);
            bfr[i] = *(const s16x8*)(&Bl[(nw + i * 16 + fr) * 32 + fq]);
        }
#pragma unroll
        for (int i = 0; i < 4; i++)
#pragma unroll
            for (int j = 0; j < 4; j++)
                acc[i][j] = __builtin_amdgcn_mfma_f32_16x16x32_bf16(af[i], bfr[j], acc[i][j], 0, 0, 0);
    }

    const int col_l = lane & 15;
    const int row_l = (lane >> 4) * 4;
#pragma unroll
    for (int i = 0; i < 4; i++)
#pragma unroll
        for (int j = 0; j < 4; j++) {
            int m_base = m0 + mw + i * 16 + row_l;   // 4 consecutive m
            int n = n0 + nw + j * 16 + col_l;
            if (MODE == 3 && n >= 2560) {
                // v: bf16 V^T, 4 consecutive si
                int nn = n - 2560;
                int bb = m_base >> 11, si = m_base & (S - 1);
                int hh = nn >> 7, d = nn & (HD - 1);
                ushort4 u;
                u.x = (unsigned short)bf16_bits(acc[i][j][0]);
                u.y = (unsigned short)bf16_bits(acc[i][j][1]);
                u.z = (unsigned short)bf16_bits(acc[i][j][2]);
                u.w = (unsigned short)bf16_bits(acc[i][j][3]);
                *(ushort4*)((bf16*)out2 + (((size_t)(bb * KV + hh)) * HD + d) * S + si) = u;
            } else {
#pragma unroll
                for (int r = 0; r < 4; r++) {
                    int m = m_base + r;
                    if (MODE == 3) {
                        int bb = m >> 11, si = m & (S - 1);
                        if (n < 2048) {
                            int h = n >> 7, d = n & (HD - 1);
                            ((float*)out0)[(((size_t)(bb * NH + h)) * S + si) * HD + d] = acc[i][j][r];
                        } else {
                            int nn = n - 2048;
                            int h = nn >> 7, d = nn & (HD - 1);
                            ((float*)out1)[(((size_t)(bb * KV + h)) * S + si) * HD + d] = acc[i][j][r];
                        }
                    } else {
                        ((float*)out0)[(size_t)m * N + n] = acc[i][j][r];
                    }
                }
            }
        }
}

// ---------------------------------------------------------------------------
// RMSNorm (over hd=128) + RoPE, q and k fused into ONE launch.
// One wave per row, zero LDS, zero barriers. Lane holds (x[d], x[d+64]);
// cos/sin tables have duplicated halves so c[d]==c[d+64].
// Rows [0, B*NH*S): q (SC=1/sqrt(hd));  rows [B*NH*S, +B*KV*S): k.
// Boundary B*NH*S = 65536 is divisible by 4 -> no block straddles it.
// ---------------------------------------------------------------------------
__global__ __launch_bounds__(256) void rms_rope_qk(const float* __restrict__ qin,
                                                   bf16* __restrict__ qout,
                                                   const float* __restrict__ qscale,
                                                   const float* __restrict__ kin,
                                                   bf16* __restrict__ kout,
                                                   const float* __restrict__ kscale,
                                                   const float* __restrict__ cosT,
                                                   const float* __restrict__ sinT) {
    int row = blockIdx.x * 4 + (threadIdx.x >> 6);
    const int lane = threadIdx.x & 63;

    const bool isq = (row < B * NH * S);
    const float* in    = isq ? qin    : kin;
    bf16*        out   = isq ? qout   : kout;
    const float* scale = isq ? qscale : kscale;
    if (!isq) row -= B * NH * S;

    const int si = row & (S - 1);
    const float* rp = in + (size_t)row * HD;

    float x1 = rp[lane];
    float x2 = rp[lane + 64];

    float ss = x1 * x1 + x2 * x2;
#pragma unroll
    for (int m = 1; m < 64; m <<= 1) ss += __shfl_xor(ss, m, 64);
    const float rinv = rsqrtf(ss * (1.0f / HD) + 1e-6f);

    const float n1 = x1 * rinv * scale[lane];
    const float n2 = x2 * rinv * scale[lane + 64];

    const float c = cosT[(size_t)si * HD + lane];
    const float s = sinT[(size_t)si * HD + lane];

    float r1 = n1 * c - n2 * s;   // d < 64: rot = -x[d+64]
    float r2 = n2 * c + n1 * s;   // d >= 64: rot = +x[d-64]
    if (isq) { r1 *= 0.08838834764831845f; r2 *= 0.08838834764831845f; }

    out[(size_t)row * HD + lane]      = __float2bfloat16(r1);
    out[(size_t)row * HD + lane + 64] = __float2bfloat16(r2);
}

// ---------------------------------------------------------------------------
// MFMA flash attention v4 (round-3/8 exact: best measured 110 us; session
// noise band ~±12 us). Head-merged, causally-paired, fixed-max softmax, TWO
// independent 4-wave groups per block (512 threads) splitting the 33-tile
// list [0,17)/[17,33). Fixed-max softmax => partial (o,l) over disjoint KV
// ranges are exactly additive; group 1 publishes its phase-B partials via
// LDS, group 0 merges. NO setprio. K AND V staged into LDS.
// qb: (b,NH,S,HD) bf16 pre-scaled by 1/sqrt(hd); kb: (b,KV,S,HD) bf16;
// vtb: (b,KV,HD,S) bf16. ctx: (b,s,nh,hd) bf16.
// Scores bounded: ||q||=||k||=sqrt(128) => |s| <= 11.32; use fixed max 13.
// ---------------------------------------------------------------------------
__global__ __launch_bounds__(512) void flash_mfma4(const bf16* __restrict__ qb,
                                                   const bf16* __restrict__ kb,
                                                   const bf16* __restrict__ vtb,
                                                   bf16* __restrict__ ctx) {
    const int p    = blockIdx.x;         // pair index 0..31
    const int kvh  = blockIdx.y;
    const int b    = blockIdx.z;
    const int tid  = threadIdx.x;
    const int wave = tid >> 6;           // 0..7
    const int grp  = wave >> 2;          // 0: list [0,17), 1: list [17,33)
    const int wl   = wave & 3;           // head within KV group
    const int lane = tid & 63;
    const int tg   = tid & 255;          // tid within group (for staging)
    const int quad = lane >> 4;
    const int l16  = lane & 15;
    const int quad8 = quad * 8;
    const int h = kvh * G + wl;          // this wave's q-head

    __shared__ __align__(16) char pool[108544];
    short* KsG = (short*)(pool + grp * 17408);           // [64][136]
    short* VsG = (short*)(pool + 34816 + grp * 18432);   // [128][72]
    short* PsW = (short*)(pool + 71680 + wave * 4608);   // [32][72]
    float* oS  = (float*)pool;
    float* lS  = (float*)(pool + 65536);

    const bf16* qbase = qb  + ((size_t)(b * NH + h))   * S * HD;
    const bf16* kbase = kb  + ((size_t)(b * KV + kvh)) * S * HD;
    const bf16* vbase = vtb + ((size_t)(b * KV + kvh)) * HD * S;

    const int nA   = (p >> 1) + 1;       // KV tiles for q-tile p (1..16)
    const int pB   = 63 - p;
    const int iBeg = grp ? 17 : 0;
    const int iEnd = grp ? 33 : 17;      // nA + nB == 33 always

    int q0 = grp ? 32 * pB : 32 * p;

    // Q A-fragments: rows q0 + s*16 + l16, k = ks*32 + quad8
    s16x8 qf[2][4];
#pragma unroll
    for (int s = 0; s < 2; s++) {
        const bf16* qrow = qbase + (size_t)(q0 + s * 16 + l16) * HD + quad8;
#pragma unroll
        for (int ks = 0; ks < 4; ks++)
            qf[s][ks] = *(const s16x8*)(qrow + ks * 32);
    }

    f32x4 o[2][8] = {};
    float l[2][4] = {};

    // prologue: prefetch this group's first tile into regs
    uint4 kreg[4], vreg[4];
    {
        const int tf = (iBeg < nA) ? 64 * iBeg : 64 * (iBeg - nA);
#pragma unroll
        for (int it = 0; it < 4; it++) {
            int c = tg + it * 256;
            kreg[it] = *(const uint4*)(kbase + (size_t)(tf + (c >> 4)) * HD + (c & 15) * 8);
            vreg[it] = *(const uint4*)(vbase + (size_t)(c >> 3) * S + tf + (c & 7) * 8);
        }
    }

    for (int ii = 0; ii < 17; ii++) {
        const int i   = iBeg + ii;
        const bool act = (i < iEnd);     // grp1 idles on ii==16 (barrier parity)

        // commit prefetched tile to this group's LDS
        if (act) {
#pragma unroll
            for (int it = 0; it < 4; it++) {
                int c = tg + it * 256;
                *(uint4*)&KsG[(c >> 4) * 136 + (c & 15) * 8] = kreg[it];
                *(uint4*)&VsG[(c >> 3) * 72  + (c & 7)  * 8] = vreg[it];
            }
        }
        __syncthreads();   // both groups' tiles ready

        const int t0 = (i < nA) ? 64 * i : 64 * (i - nA);

        // issue next tile's global loads (in flight during compute)
        if (act && i + 1 < iEnd) {
            const int tn = (i + 1 < nA) ? 64 * (i + 1) : 64 * (i + 1 - nA);
#pragma unroll
            for (int it = 0; it < 4; it++) {
                int c = tg + it * 256;
                kreg[it] = *(const uint4*)(kbase + (size_t)(tn + (c >> 4)) * HD + (c & 15) * 8);
                vreg[it] = *(const uint4*)(vbase + (size_t)(c >> 3) * S + tn + (c & 7) * 8);
            }
        }

        if (act) {
            // ---- S = Q K^T : 32q x 64t per wave ----
            f32x4 sa[2][4] = {};
#pragma unroll
            for (int ks = 0; ks < 4; ks++) {
#pragma unroll
                for (int n = 0; n < 4; n++) {
                    s16x8 kf = *(const s16x8*)&KsG[(n * 16 + l16) * 136 + ks * 32 + quad8];
#pragma unroll
                    for (int s = 0; s < 2; s++)
                        sa[s][n] = __builtin_amdgcn_mfma_f32_16x16x32_bf16(qf[s][ks], kf, sa[s][n], 0, 0, 0);
                }
            }

            // ---- fixed-max exp: p = exp(s - 13); no reductions, no rescale ----
            const bool msk = (t0 + 63 > q0);  // only possibly true on a phase's last tile
#pragma unroll
            for (int s = 0; s < 2; s++)
#pragma unroll
                for (int r = 0; r < 4; r++) {
                    const int qg = q0 + s * 16 + quad * 4 + r;
#pragma unroll
                    for (int n = 0; n < 4; n++) {
                        float v = sa[s][n][r];
                        if (msk && (t0 + n * 16 + l16 > qg)) v = -INFINITY;
                        float pv = __expf(v - 13.0f);
                        l[s][r] += pv;
                        PsW[(s * 16 + quad * 4 + r) * 72 + n * 16 + l16] = bf16_bits(pv);
                    }
                }
            // Ps is per-wave: same-wave LDS write->read needs no barrier (proven R6).

            // ---- PV: O(32q x 128d) += P(32x64) V(64x128) ----
#pragma unroll
            for (int ks = 0; ks < 2; ks++) {
                s16x8 vf[8];
#pragma unroll
                for (int n = 0; n < 8; n++)
                    vf[n] = *(const s16x8*)&VsG[(n * 16 + l16) * 72 + ks * 32 + quad8];
#pragma unroll
                for (int s = 0; s < 2; s++) {
                    s16x8 pf = *(const s16x8*)&PsW[(s * 16 + l16) * 72 + ks * 32 + quad8];
#pragma unroll
                    for (int n = 0; n < 8; n++)
                        o[s][n] = __builtin_amdgcn_mfma_f32_16x16x32_bf16(pf, vf[n], o[s][n], 0, 0, 0);
                }
            }

            // ---- phase boundary (group 0 only; group 1's i >= 17 > nA-1):
            //      flush complete phase A, switch to q-tile 63-p ----
            if (i == nA - 1) {
#pragma unroll
                for (int s = 0; s < 2; s++)
#pragma unroll
                    for (int r = 0; r < 4; r++) {
                        float ls = l[s][r];
#pragma unroll
                        for (int m = 1; m < 16; m <<= 1) ls += __shfl_xor(ls, m, 64);
                        const float inv = 1.0f / ls;
                        const int qg = q0 + s * 16 + quad * 4 + r;
                        bf16* dst = ctx + (((size_t)(b * S + qg)) * NH + h) * HD;
#pragma unroll
                        for (int n = 0; n < 8; n++)
                            dst[n * 16 + l16] = __float2bfloat16(o[s][n][r] * inv);
                    }
                q0 = 32 * pB;
#pragma unroll
                for (int s = 0; s < 2; s++) {
                    const bf16* qrow = qbase + (size_t)(q0 + s * 16 + l16) * HD + quad8;
#pragma unroll
                    for (int ks = 0; ks < 4; ks++)
                        qf[s][ks] = *(const s16x8*)(qrow + ks * 32);
                }
#pragma unroll
                for (int s = 0; s < 2; s++) {
#pragma unroll
                    for (int n = 0; n < 8; n++) o[s][n] = (f32x4){0.f, 0.f, 0.f, 0.f};
#pragma unroll
                    for (int r = 0; r < 4; r++) l[s][r] = 0.0f;
                }
            }
        }

        __syncthreads();   // all waves done reading Ks/Vs before next commit
    }

    // ---- merge phase-B partials: grp1 -> LDS, grp0 adds + writes ----
    // (fixed-max softmax: disjoint-KV partials are additive in o and l)
    if (grp == 1) {
        float* oW = oS + wl * 64 * 64;
        float* lW = lS + wl * 8 * 64;
#pragma unroll
        for (int s = 0; s < 2; s++)
#pragma unroll
            for (int n = 0; n < 8; n++)
#pragma unroll
                for (int r = 0; r < 4; r++)
                    oW[((s * 8 + n) * 4 + r) * 64 + lane] = o[s][n][r];
#pragma unroll
        for (int s = 0; s < 2; s++)
#pragma unroll
            for (int r = 0; r < 4; r++)
                lW[(s * 4 + r) * 64 + lane] = l[s][r];
    }
    __syncthreads();
    if (grp == 0) {
        float* oW = oS + wl * 64 * 64;
        float* lW = lS + wl * 8 * 64;
#pragma unroll
        for (int s = 0; s < 2; s++)
#pragma unroll
            for (int r = 0; r < 4; r++) {
                float ls = l[s][r] + lW[(s * 4 + r) * 64 + lane];
#pragma unroll
                for (int m = 1; m < 16; m <<= 1) ls += __shfl_xor(ls, m, 64);
                const float inv = 1.0f / ls;
                const int qg = q0 + s * 16 + quad * 4 + r;   // q0 == 32*pB here
                bf16* dst = ctx + (((size_t)(b * S + qg)) * NH + h) * HD;
#pragma unroll
                for (int n = 0; n < 8; n++)
                    dst[n * 16 + l16] =
                        __float2bfloat16((o[s][n][r] + oW[((s * 8 + n) * 4 + r) * 64 + lane]) * inv);
            }
    }
}

// ---------------------------------------------------------------------------
extern "C" void kernel_launch(void* const* d_in, const int* in_sizes, int n_in,
                              void* d_out, int out_size, void* d_ws, size_t ws_size,
                              hipStream_t stream) {
    const float* x    = (const float*)d_in[0];
    const float* cosT = (const float*)d_in[2];
    const float* sinT = (const float*)d_in[3];
    const float* Wq   = (const float*)d_in[4];
    const float* Wk   = (const float*)d_in[5];
    const float* Wv   = (const float*)d_in[6];
    const float* Wo   = (const float*)d_in[7];
    const float* qsc  = (const float*)d_in[8];
    const float* ksc  = (const float*)d_in[9];
    float* out = (float*)d_out;

    // Workspace packing (72 MB total), byte offsets:
    // q_ws [0,32M) fp32 q head-major; wo_t [0,8M) after q dead;
    // ctx_b [8M,24M) after q dead; k_ws [32M,40M) fp32 k head-major;
    // xb [40M,56M); qb same region after projections;
    // wq_t [56M,64M), wk_t [64M,66M), wv_t [66M,68M) = contiguous Wqkv^T (N=3072);
    // kb [56M,64M) same region after projections; vtb [68M,72M).
    char* w = (char*)d_ws;
    float* q_ws = (float*)(w);
    bf16*  wo_t = (bf16*)(w);
    bf16*  ctx_b= (bf16*)(w + (8u << 20));
    float* k_ws = (float*)(w + (32u << 20));
    bf16*  xb   = (bf16*)(w + (40u << 20));
    bf16*  qb   = (bf16*)(w + (40u << 20));
    bf16*  wq_t = (bf16*)(w + (56u << 20));
    bf16*  kb   = (bf16*)(w + (56u << 20));
    bf16*  wk_t = (bf16*)(w + (64u << 20));
    bf16*  wv_t = (bf16*)(w + (66u << 20));
    bf16*  vtb  = (bf16*)(w + (68u << 20));

    // 1) fused prep: x cast + Wq/Wk/Wv transpose-casts (one launch)
    prep<<<dim3(8192 + 4096 + 1024 + 1024), 256, 0, stream>>>(
        x, xb, Wq, wq_t, Wk, wk_t, Wv, wv_t);

    // 2) fused QKV projection (MFMA, N=3072): q,k -> fp32 head-major; v -> bf16 V^T
    gemm_bt<3><<<dim3((NH * HD + 2 * KV * HD) / 128, M_ROWS / 128), 256, 0, stream>>>(
        xb, wq_t, q_ws, k_ws, vtb, NH * HD + 2 * KV * HD, D);

    // 3) RMSNorm + RoPE for q AND k, one launch
    rms_rope_qk<<<dim3((B * NH * S + B * KV * S) / 4), 256, 0, stream>>>(
        q_ws, qb, qsc, k_ws, kb, ksc, cosT, sinT);

    // 4) Wo^T into dead q region (must follow rms: dest overlays q_ws)
    tcast<<<dim3(D / 32, D / 32), 256, 0, stream>>>(Wo, wo_t, D, D);

    // 5) MFMA flash attention v4 (round-3 grid, best measured) -> bf16 ctx
    flash_mfma4<<<dim3(32, KV, B), 512, 0, stream>>>(qb, kb, vtb, ctx_b);

    // 6) output projection
    gemm_bt<0><<<dim3(D / 128, M_ROWS / 128), 256, 0, stream>>>(ctx_b, wo_t, out, nullptr, nullptr, D, D);
}